// Round 1
// baseline (739.582 us; speedup 1.0000x reference)
//
#include <hip/hip_runtime.h>

// Problem constants (fixed by setup_inputs)
#define B_ 8
#define T_ 2048
#define C_ 1024
#define H_ 4096
#define E_ 8
#define S_ (2 * T_)          // slots per batch row (K=2)
#define CAP 320              // int(T/E * 1.25)
#define NROWS (E_ * B_ * CAP) // 20480 bucket rows

typedef __attribute__((ext_vector_type(8))) short short8;
typedef __attribute__((ext_vector_type(4))) float f32x4;

__device__ __forceinline__ unsigned short f2bf(float f) {
  unsigned u = __float_as_uint(f);
  unsigned r = 0x7FFFu + ((u >> 16) & 1u);   // RNE, no NaN in this data
  return (unsigned short)((u + r) >> 16);
}

__device__ __forceinline__ void gload_lds16(const void* g, void* l) {
  __builtin_amdgcn_global_load_lds(
      (const __attribute__((address_space(1))) unsigned int*)g,
      (__attribute__((address_space(3))) unsigned int*)l, 16, 0, 0);
}

// ---------------- conversion kernels ----------------
__global__ void cvt_f32_bf16(const float* __restrict__ in,
                             unsigned short* __restrict__ out, long n4) {
  long i = (long)blockIdx.x * blockDim.x + threadIdx.x;
  if (i >= n4) return;
  float4 v = ((const float4*)in)[i];
  union { unsigned short u[4]; unsigned long long ll; } o;
  o.u[0] = f2bf(v.x); o.u[1] = f2bf(v.y); o.u[2] = f2bf(v.z); o.u[3] = f2bf(v.w);
  ((unsigned long long*)out)[i] = o.ll;
}

// in: [R][Cc] fp32 (expert blockIdx.z) -> out: [Cc][R] bf16
__global__ void cvt_transpose(const float* __restrict__ in,
                              unsigned short* __restrict__ out, int R, int Cc) {
  __shared__ float t[64][65];
  const int tid = threadIdx.x;
  const long eoff = (long)blockIdx.z * R * Cc;
  const int r0 = blockIdx.x * 64, c0 = blockIdx.y * 64;
#pragma unroll
  for (int it = 0; it < 4; ++it) {
    int r = it * 16 + (tid >> 4);
    int c = (tid & 15) * 4;
    float4 v = *(const float4*)(in + eoff + (long)(r0 + r) * Cc + c0 + c);
    t[r][c] = v.x; t[r][c + 1] = v.y; t[r][c + 2] = v.z; t[r][c + 3] = v.w;
  }
  __syncthreads();
#pragma unroll
  for (int it = 0; it < 4; ++it) {
    int oc = it * 16 + (tid >> 4);   // column index (output row c0+oc)
    int orr = (tid & 15) * 4;        // original rows r0+orr..+3 (output cols)
    union { unsigned short u[4]; unsigned long long ll; } o;
    o.u[0] = f2bf(t[orr + 0][oc]); o.u[1] = f2bf(t[orr + 1][oc]);
    o.u[2] = f2bf(t[orr + 2][oc]); o.u[3] = f2bf(t[orr + 3][oc]);
    *(unsigned long long*)(out + eoff + (long)(c0 + oc) * R + r0 + orr) = o.ll;
  }
}

// ---------------- router: one wave per token ----------------
__global__ void router(const float* __restrict__ x, const float* __restrict__ Wr,
                       int* __restrict__ es, float* __restrict__ ps) {
  const int token = blockIdx.x * 4 + (threadIdx.x >> 6);
  const int lane = threadIdx.x & 63;
  const float* xr = x + (long)token * C_;
  float acc[8] = {0, 0, 0, 0, 0, 0, 0, 0};
#pragma unroll
  for (int j = 0; j < 16; ++j) {
    int c = j * 64 + lane;
    float xv = xr[c];
    const float4* wr = (const float4*)(Wr + c * 8);
    float4 w0 = wr[0], w1 = wr[1];
    acc[0] += xv * w0.x; acc[1] += xv * w0.y; acc[2] += xv * w0.z; acc[3] += xv * w0.w;
    acc[4] += xv * w1.x; acc[5] += xv * w1.y; acc[6] += xv * w1.z; acc[7] += xv * w1.w;
  }
#pragma unroll
  for (int off = 32; off >= 1; off >>= 1)
#pragma unroll
    for (int e = 0; e < 8; ++e) acc[e] += __shfl_xor(acc[e], off);
  // softmax over 8 (all lanes redundantly)
  float mx = acc[0];
#pragma unroll
  for (int e = 1; e < 8; ++e) mx = fmaxf(mx, acc[e]);
  float pr[8], se = 0.f;
#pragma unroll
  for (int e = 0; e < 8; ++e) { pr[e] = expf(acc[e] - mx); se += pr[e]; }
  float inv = 1.f / se;
  // top-2 on probs, jax tie-break: lower index wins on equality (strict >)
  int e0 = 0; float v0 = pr[0];
#pragma unroll
  for (int e = 1; e < 8; ++e) if (pr[e] > v0) { v0 = pr[e]; e0 = e; }
  int e1 = -1; float v1 = -1.f;
#pragma unroll
  for (int e = 0; e < 8; ++e) if (e != e0 && pr[e] > v1) { v1 = pr[e]; e1 = e; }
  if (lane == 0) {
    es[2 * token] = e0;     ps[2 * token] = v0 * inv;
    es[2 * token + 1] = e1; ps[2 * token + 1] = v1 * inv;
  }
}

// ---------------- positions: sequential scan per batch row ----------------
__global__ void positions(const int* __restrict__ es, int* __restrict__ pos,
                          int* __restrict__ tsrc) {
  const int b = blockIdx.x;
  const int lane = threadIdx.x;  // 64 threads
  int cnt[8] = {0, 0, 0, 0, 0, 0, 0, 0};
  unsigned long long below = (1ULL << lane) - 1ULL;
  int e_next = es[(long)b * S_ + lane];
  for (int chunk = 0; chunk < S_ / 64; ++chunk) {
    int e = e_next;
    if (chunk + 1 < S_ / 64) e_next = es[(long)b * S_ + (chunk + 1) * 64 + lane];
    int myPos = 0;
#pragma unroll
    for (int ei = 0; ei < 8; ++ei) {
      unsigned long long m = __ballot(e == ei);
      if (e == ei) myPos = cnt[ei] + __popcll(m & below);
      cnt[ei] += __popcll(m);
    }
    int s = chunk * 64 + lane;
    pos[(long)b * S_ + s] = myPos;
    if (myPos < CAP) tsrc[((long)e * B_ + b) * CAP + myPos] = s >> 1;  // token t
  }
}

// ---------------- grouped MFMA GEMM (shared for GEMM1/GEMM2) ----------------
// A (bf16): GATHER ? x_bf [B*T][Kdim] gathered via tsrc : h [NROWS][Kdim]
// BT (bf16): [E][N][Kdim] (pre-transposed weights, K-contiguous)
// out: RELU_BF16 ? bf16 h [NROWS][N] (relu(acc+bias)) : fp32 y [NROWS][N] (acc+bias)
template <bool GATHER, bool RELU_BF16>
__global__ __launch_bounds__(256) void moe_gemm(
    const unsigned short* __restrict__ A, const unsigned short* __restrict__ BT,
    const float* __restrict__ bias, const int* __restrict__ tsrc,
    void* __restrict__ outp, const int Kdim, const int N) {
  constexpr int BM = 64, BN = 128, BK = 64;
  __shared__ unsigned short As[BM * BK];  // 8 KB, XOR-swizzled 16B slots
  __shared__ unsigned short Bs[BN * BK];  // 16 KB
  const int tid = threadIdx.x, lane = tid & 63, w = tid >> 6;
  const int group = blockIdx.x / (CAP / BM);
  const int mt = blockIdx.x % (CAP / BM);
  const int e = group >> 3, b = group & 7;
  const int n0 = blockIdx.y * BN;

  // staging sources: wave w covers A rows [w*16,w*16+16) in 2 issues,
  // B rows [w*32,w*32+32) in 4 issues; lane -> row base + lane/8, 16B slot lane&7.
  // Source slot pre-swizzled (j ^ (row&7)) so that linear global_load_lds dest +
  // swizzled ds_read are a consistent involution (guide rule #21).
  long a_src[2];
#pragma unroll
  for (int i = 0; i < 2; ++i) {
    int ra = w * 16 + i * 8 + (lane >> 3);
    int j = lane & 7;
    long rowbase;
    if constexpr (GATHER) {
      int tok = tsrc[(long)group * CAP + mt * BM + ra];
      if (tok < 0) tok = 0;  // empty bucket row: compute garbage, never gathered
      rowbase = ((long)(b * T_ + tok)) * Kdim;
    } else {
      rowbase = ((long)group * CAP + mt * BM + ra) * (long)Kdim;
    }
    a_src[i] = rowbase + ((j ^ (ra & 7)) << 3);
  }
  long b_src[4];
#pragma unroll
  for (int i = 0; i < 4; ++i) {
    int rb = w * 32 + i * 8 + (lane >> 3);
    int j = lane & 7;
    b_src[i] = ((long)e * N + n0 + rb) * (long)Kdim + ((j ^ (rb & 7)) << 3);
  }

  const int wm = w >> 1, wn = w & 1;
  f32x4 acc[2][4];
#pragma unroll
  for (int m = 0; m < 2; ++m)
#pragma unroll
    for (int n = 0; n < 4; ++n) acc[m][n] = (f32x4){0.f, 0.f, 0.f, 0.f};

  const int arow[2] = {wm * 32 + (lane & 15), wm * 32 + 16 + (lane & 15)};
  const int brow[4] = {wn * 64 + (lane & 15), wn * 64 + 16 + (lane & 15),
                       wn * 64 + 32 + (lane & 15), wn * 64 + 48 + (lane & 15)};
  const int jjb = lane >> 4;

  for (int k0 = 0; k0 < Kdim; k0 += BK) {
#pragma unroll
    for (int i = 0; i < 2; ++i)
      gload_lds16(A + a_src[i] + k0, &As[(w * 16 + i * 8) * BK]);
#pragma unroll
    for (int i = 0; i < 4; ++i)
      gload_lds16(BT + b_src[i] + k0, &Bs[(w * 32 + i * 8) * BK]);
    __syncthreads();
#pragma unroll
    for (int s = 0; s < 2; ++s) {
      short8 af[2], bf[4];
#pragma unroll
      for (int m = 0; m < 2; ++m) {
        int slot = (s * 4 + jjb) ^ (arow[m] & 7);
        af[m] = *(const short8*)&As[arow[m] * BK + slot * 8];
      }
#pragma unroll
      for (int n = 0; n < 4; ++n) {
        int slot = (s * 4 + jjb) ^ (brow[n] & 7);
        bf[n] = *(const short8*)&Bs[brow[n] * BK + slot * 8];
      }
#pragma unroll
      for (int m = 0; m < 2; ++m)
#pragma unroll
        for (int n = 0; n < 4; ++n)
          acc[m][n] = __builtin_amdgcn_mfma_f32_16x16x32_bf16(af[m], bf[n],
                                                              acc[m][n], 0, 0, 0);
    }
    __syncthreads();
  }

  // epilogue: C/D layout col=lane&15, row=(lane>>4)*4+j  [m89]
  const long rbase = (long)group * CAP + mt * BM;
#pragma unroll
  for (int m = 0; m < 2; ++m) {
#pragma unroll
    for (int n = 0; n < 4; ++n) {
      const int trow = wm * 32 + m * 16 + ((lane >> 4) << 2);
      const int col = n0 + wn * 64 + n * 16 + (lane & 15);
      const float bv = bias[(long)e * N + col];
#pragma unroll
      for (int j = 0; j < 4; ++j) {
        float v = acc[m][n][j] + bv;
        const long orow = rbase + trow + j;
        if constexpr (RELU_BF16) {
          v = fmaxf(v, 0.f);
          ((unsigned short*)outp)[orow * N + col] = f2bf(v);
        } else {
          ((float*)outp)[orow * N + col] = v;
        }
      }
    }
  }
}

// ---------------- combine ----------------
__global__ void combine(const float* __restrict__ y, const int* __restrict__ es,
                        const float* __restrict__ ps, const int* __restrict__ pos,
                        float* __restrict__ out) {
  const int token = blockIdx.x;  // b*T + t
  const int b = token >> 11;     // T = 2048
  const int s0 = 2 * token, s1 = s0 + 1;
  int e0 = es[s0], e1 = es[s1];
  int q0 = pos[s0], q1 = pos[s1];
  float p0 = ps[s0], p1 = ps[s1];
  const bool k0 = q0 < CAP, k1 = q1 < CAP;
  if (q0 > CAP - 1) q0 = CAP - 1;
  if (q1 > CAP - 1) q1 = CAP - 1;
  const float4* r0 = (const float4*)(y + ((long)(e0 * B_ + b) * CAP + q0) * C_);
  const float4* r1 = (const float4*)(y + ((long)(e1 * B_ + b) * CAP + q1) * C_);
  const int c = threadIdx.x;  // 256 threads x float4 = 1024
  float4 a = {0.f, 0.f, 0.f, 0.f};
  if (k0) {
    float4 v = r0[c];
    a.x += p0 * v.x; a.y += p0 * v.y; a.z += p0 * v.z; a.w += p0 * v.w;
  }
  if (k1) {
    float4 v = r1[c];
    a.x += p1 * v.x; a.y += p1 * v.y; a.z += p1 * v.z; a.w += p1 * v.w;
  }
  ((float4*)(out + (long)token * C_))[c] = a;
}

// ---------------- launch ----------------
extern "C" void kernel_launch(void* const* d_in, const int* in_sizes, int n_in,
                              void* d_out, int out_size, void* d_ws, size_t ws_size,
                              hipStream_t stream) {
  const float* x = (const float*)d_in[0];
  const float* Wr = (const float*)d_in[1];
  const float* W1 = (const float*)d_in[2];
  const float* b1 = (const float*)d_in[3];
  const float* W2 = (const float*)d_in[4];
  const float* b2 = (const float*)d_in[5];
  float* out = (float*)d_out;
  char* ws = (char*)d_ws;
  // workspace layout (needs ~400.5 MB)
  unsigned short* x_bf = (unsigned short*)(ws + 0L);          // 33,554,432
  unsigned short* W1T = (unsigned short*)(ws + 33554432L);    // 67,108,864  [E][H][C]
  unsigned short* W2T = (unsigned short*)(ws + 100663296L);   // 67,108,864  [E][C][H]
  unsigned short* h = (unsigned short*)(ws + 167772160L);     // 167,772,160 [NROWS][H]
  float* y = (float*)(ws + 335544320L);                       // 83,886,080  [NROWS][C]
  int* es = (int*)(ws + 419430400L);                          // 131,072
  float* ps = (float*)(ws + 419561472L);                      // 131,072
  int* pos = (int*)(ws + 419692544L);                         // 131,072
  int* tsrc = (int*)(ws + 419823616L);                        // 81,920

  cvt_f32_bf16<<<16384, 256, 0, stream>>>(x, x_bf, (long)B_ * T_ * C_ / 4);
  cvt_transpose<<<dim3(16, 64, 8), 256, 0, stream>>>(W1, W1T, C_, H_);
  cvt_transpose<<<dim3(64, 16, 8), 256, 0, stream>>>(W2, W2T, H_, C_);
  router<<<4096, 256, 0, stream>>>(x, Wr, es, ps);
  hipMemsetAsync(tsrc, 0xFF, NROWS * sizeof(int), stream);
  positions<<<8, 64, 0, stream>>>(es, pos, tsrc);
  moe_gemm<true, true><<<dim3(320, 32), 256, 0, stream>>>(x_bf, W1T, b1, tsrc, h, C_, H_);
  moe_gemm<false, false><<<dim3(320, 8), 256, 0, stream>>>(h, W2T, b2, nullptr, y, H_, C_);
  combine<<<16384, 256, 0, stream>>>(y, es, ps, pos, out);
}

// Round 2
// 660.316 us; speedup vs baseline: 1.1200x; 1.1200x over previous
//
#include <hip/hip_runtime.h>

// Problem constants (fixed by setup_inputs)
#define B_ 8
#define T_ 2048
#define C_ 1024
#define H_ 4096
#define E_ 8
#define S_ (2 * T_)          // slots per batch row (K=2)
#define CAP 320              // int(T/E * 1.25)
#define ME 2560              // rows per expert = B_*CAP (20 x 128)
#define NROWS (E_ * ME)      // 20480 bucket rows

typedef __attribute__((ext_vector_type(8))) short short8;
typedef __attribute__((ext_vector_type(4))) float f32x4;

__device__ __forceinline__ unsigned short f2bf(float f) {
  unsigned u = __float_as_uint(f);
  unsigned r = 0x7FFFu + ((u >> 16) & 1u);   // RNE, no NaN in this data
  return (unsigned short)((u + r) >> 16);
}

__device__ __forceinline__ void gload_lds16(const void* g, void* l) {
  __builtin_amdgcn_global_load_lds(
      (const __attribute__((address_space(1))) unsigned int*)g,
      (__attribute__((address_space(3))) unsigned int*)l, 16, 0, 0);
}

// ---------------- weight transpose+convert ----------------
// in: [R][Cc] fp32 (expert blockIdx.z) -> out: [Cc][R] bf16
__global__ void cvt_transpose(const float* __restrict__ in,
                              unsigned short* __restrict__ out, int R, int Cc) {
  __shared__ float t[64][65];
  const int tid = threadIdx.x;
  const long eoff = (long)blockIdx.z * R * Cc;
  const int r0 = blockIdx.x * 64, c0 = blockIdx.y * 64;
#pragma unroll
  for (int it = 0; it < 4; ++it) {
    int r = it * 16 + (tid >> 4);
    int c = (tid & 15) * 4;
    float4 v = *(const float4*)(in + eoff + (long)(r0 + r) * Cc + c0 + c);
    t[r][c] = v.x; t[r][c + 1] = v.y; t[r][c + 2] = v.z; t[r][c + 3] = v.w;
  }
  __syncthreads();
#pragma unroll
  for (int it = 0; it < 4; ++it) {
    int oc = it * 16 + (tid >> 4);   // column index (output row c0+oc)
    int orr = (tid & 15) * 4;        // original rows r0+orr..+3 (output cols)
    union { unsigned short u[4]; unsigned long long ll; } o;
    o.u[0] = f2bf(t[orr + 0][oc]); o.u[1] = f2bf(t[orr + 1][oc]);
    o.u[2] = f2bf(t[orr + 2][oc]); o.u[3] = f2bf(t[orr + 3][oc]);
    *(unsigned long long*)(out + eoff + (long)(c0 + oc) * R + r0 + orr) = o.ll;
  }
}

// ---------------- fused router + x->bf16 convert: one wave per token --------
__global__ void router_cvt(const float* __restrict__ x, const float* __restrict__ Wr,
                           int* __restrict__ es, float* __restrict__ ps,
                           unsigned short* __restrict__ x_bf) {
  const int token = blockIdx.x * 4 + (threadIdx.x >> 6);
  const int lane = threadIdx.x & 63;
  const float* xr = x + (long)token * C_;
  float acc[8] = {0, 0, 0, 0, 0, 0, 0, 0};
#pragma unroll
  for (int j = 0; j < 4; ++j) {
    int c = j * 256 + lane * 4;
    float4 xv = *(const float4*)(xr + c);
    // bf16 write (4 elems, 8B)
    union { unsigned short u[4]; unsigned long long ll; } o;
    o.u[0] = f2bf(xv.x); o.u[1] = f2bf(xv.y); o.u[2] = f2bf(xv.z); o.u[3] = f2bf(xv.w);
    *(unsigned long long*)(x_bf + (long)token * C_ + c) = o.ll;
    const float xe[4] = {xv.x, xv.y, xv.z, xv.w};
#pragma unroll
    for (int i = 0; i < 4; ++i) {
      const float4* wr = (const float4*)(Wr + (long)(c + i) * 8);
      float4 w0 = wr[0], w1 = wr[1];
      float v = xe[i];
      acc[0] += v * w0.x; acc[1] += v * w0.y; acc[2] += v * w0.z; acc[3] += v * w0.w;
      acc[4] += v * w1.x; acc[5] += v * w1.y; acc[6] += v * w1.z; acc[7] += v * w1.w;
    }
  }
#pragma unroll
  for (int off = 32; off >= 1; off >>= 1)
#pragma unroll
    for (int e = 0; e < 8; ++e) acc[e] += __shfl_xor(acc[e], off);
  float mx = acc[0];
#pragma unroll
  for (int e = 1; e < 8; ++e) mx = fmaxf(mx, acc[e]);
  float pr[8], se = 0.f;
#pragma unroll
  for (int e = 0; e < 8; ++e) { pr[e] = expf(acc[e] - mx); se += pr[e]; }
  float inv = 1.f / se;
  // top-2 on probs, jax tie-break: lower index wins on equality (strict >)
  int e0 = 0; float v0 = pr[0];
#pragma unroll
  for (int e = 1; e < 8; ++e) if (pr[e] > v0) { v0 = pr[e]; e0 = e; }
  int e1 = -1; float v1 = -1.f;
#pragma unroll
  for (int e = 0; e < 8; ++e) if (e != e0 && pr[e] > v1) { v1 = pr[e]; e1 = e; }
  if (lane == 0) {
    es[2 * token] = e0;     ps[2 * token] = v0 * inv;
    es[2 * token + 1] = e1; ps[2 * token + 1] = v1 * inv;
  }
}

// ---------------- positions: sequential scan per batch row ----------------
// tsrc[e*ME + b*CAP + pos] = global x row (b*T + t); -1 where bucket empty.
__global__ void positions(const int* __restrict__ es, int* __restrict__ pos,
                          int* __restrict__ tsrc) {
  const int b = blockIdx.x;
  const int lane = threadIdx.x;  // 64 threads
  int cnt[8] = {0, 0, 0, 0, 0, 0, 0, 0};
  unsigned long long below = (1ULL << lane) - 1ULL;
  int e_next = es[(long)b * S_ + lane];
  for (int chunk = 0; chunk < S_ / 64; ++chunk) {
    int e = e_next;
    if (chunk + 1 < S_ / 64) e_next = es[(long)b * S_ + (chunk + 1) * 64 + lane];
    int myPos = 0;
#pragma unroll
    for (int ei = 0; ei < 8; ++ei) {
      unsigned long long m = __ballot(e == ei);
      if (e == ei) myPos = cnt[ei] + __popcll(m & below);
      cnt[ei] += __popcll(m);
    }
    int s = chunk * 64 + lane;
    pos[(long)b * S_ + s] = myPos;
    if (myPos < CAP)
      tsrc[(long)e * ME + b * CAP + myPos] = b * T_ + (s >> 1);
  }
}

// ---------------- grouped MFMA GEMM, m97 structure (128x128 tile) ----------
// Per-expert M space = ME (2560) contiguous rows. 1D grid, XCD-chunked so each
// XCD owns one expert: bid_lin = e*(MT*NT) + nt*MT + mt (mt fastest -> B-panel
// L2 reuse x20).
// A (bf16): GATHER ? x_bf [B*T][Kdim] gathered via tsrc : h [NROWS][Kdim]
// BT (bf16): [E][N][Kdim] (pre-transposed, K-contiguous)
// out: RELU_BF16 ? bf16 h (relu(acc+bias)) : fp32 y (acc+bias)
template <bool GATHER, bool RELU_BF16>
__global__ __launch_bounds__(256) void moe_gemm(
    const unsigned short* __restrict__ A, const unsigned short* __restrict__ BT,
    const float* __restrict__ bias, const int* __restrict__ tsrc,
    void* __restrict__ outp, const int Kdim, const int N, const int NT) {
  constexpr int BM = 128, BN = 128, BK = 64;
  constexpr int MT = ME / BM;  // 20
  __shared__ unsigned short As[BM * BK];  // 16 KB, XOR-swizzled 16B slots
  __shared__ unsigned short Bs[BN * BK];  // 16 KB
  const int tid = threadIdx.x, lane = tid & 63, w = tid >> 6;

  // XCD-aware swizzle: grid = E_*NT*MT, always divisible by 8.
  const int nwg = E_ * NT * MT;
  const int chunk = nwg >> 3;
  const int swz = (blockIdx.x & 7) * chunk + (blockIdx.x >> 3);
  const int e = swz / (NT * MT);
  const int rem = swz % (NT * MT);
  const int nt = rem / MT, mt = rem % MT;
  const int n0 = nt * BN;

  // staging: wave w covers A rows [w*32,w*32+32) in 4 issues of 8 rows; same B.
  // LDS linear dest + pre-swizzled global source slot (j ^ (row&7)) so the
  // swizzled ds_read below is the matching involution (guide rule #21).
  long a_src[4];
#pragma unroll
  for (int i = 0; i < 4; ++i) {
    int ra = w * 32 + i * 8 + (lane >> 3);
    int j = lane & 7;
    long rowbase;
    if constexpr (GATHER) {
      int xrow = tsrc[(long)e * ME + mt * BM + ra];
      if (xrow < 0) xrow = 0;  // empty bucket row: garbage, never gathered back
      rowbase = (long)xrow * Kdim;
    } else {
      rowbase = ((long)e * ME + mt * BM + ra) * (long)Kdim;
    }
    a_src[i] = rowbase + ((j ^ (ra & 7)) << 3);
  }
  long b_src[4];
#pragma unroll
  for (int i = 0; i < 4; ++i) {
    int rb = w * 32 + i * 8 + (lane >> 3);
    int j = lane & 7;
    b_src[i] = ((long)e * N + n0 + rb) * (long)Kdim + ((j ^ (rb & 7)) << 3);
  }

  const int wm = w >> 1, wn = w & 1;   // 2x2 waves, each 64x64 output
  f32x4 acc[4][4];
#pragma unroll
  for (int m = 0; m < 4; ++m)
#pragma unroll
    for (int n = 0; n < 4; ++n) acc[m][n] = (f32x4){0.f, 0.f, 0.f, 0.f};

  int arow[4], brow[4];
#pragma unroll
  for (int i = 0; i < 4; ++i) {
    arow[i] = wm * 64 + i * 16 + (lane & 15);
    brow[i] = wn * 64 + i * 16 + (lane & 15);
  }
  const int jjb = lane >> 4;

  for (int k0 = 0; k0 < Kdim; k0 += BK) {
#pragma unroll
    for (int i = 0; i < 4; ++i)
      gload_lds16(A + a_src[i] + k0, &As[(w * 32 + i * 8) * BK]);
#pragma unroll
    for (int i = 0; i < 4; ++i)
      gload_lds16(BT + b_src[i] + k0, &Bs[(w * 32 + i * 8) * BK]);
    __syncthreads();
#pragma unroll
    for (int s = 0; s < 2; ++s) {
      short8 af[4], bf[4];
#pragma unroll
      for (int m = 0; m < 4; ++m) {
        int slot = (s * 4 + jjb) ^ (arow[m] & 7);
        af[m] = *(const short8*)&As[arow[m] * BK + slot * 8];
      }
#pragma unroll
      for (int n = 0; n < 4; ++n) {
        int slot = (s * 4 + jjb) ^ (brow[n] & 7);
        bf[n] = *(const short8*)&Bs[brow[n] * BK + slot * 8];
      }
#pragma unroll
      for (int m = 0; m < 4; ++m)
#pragma unroll
        for (int n = 0; n < 4; ++n)
          acc[m][n] = __builtin_amdgcn_mfma_f32_16x16x32_bf16(af[m], bf[n],
                                                              acc[m][n], 0, 0, 0);
    }
    __syncthreads();
  }

  // epilogue: C/D layout col=lane&15, row=(lane>>4)*4+j  [m89]
  const long rbase = (long)e * ME + mt * BM;
#pragma unroll
  for (int m = 0; m < 4; ++m) {
#pragma unroll
    for (int n = 0; n < 4; ++n) {
      const int trow = wm * 64 + m * 16 + ((lane >> 4) << 2);
      const int col = n0 + wn * 64 + n * 16 + (lane & 15);
      const float bv = bias[(long)e * N + col];
#pragma unroll
      for (int j = 0; j < 4; ++j) {
        float v = acc[m][n][j] + bv;
        const long orow = rbase + trow + j;
        if constexpr (RELU_BF16) {
          v = fmaxf(v, 0.f);
          ((unsigned short*)outp)[orow * N + col] = f2bf(v);
        } else {
          ((float*)outp)[orow * N + col] = v;
        }
      }
    }
  }
}

// ---------------- combine ----------------
__global__ void combine(const float* __restrict__ y, const int* __restrict__ es,
                        const float* __restrict__ ps, const int* __restrict__ pos,
                        float* __restrict__ out) {
  const int token = blockIdx.x;  // b*T + t
  const int b = token >> 11;     // T = 2048
  const int s0 = 2 * token, s1 = s0 + 1;
  int e0 = es[s0], e1 = es[s1];
  int q0 = pos[s0], q1 = pos[s1];
  float p0 = ps[s0], p1 = ps[s1];
  const bool k0 = q0 < CAP, k1 = q1 < CAP;
  if (q0 > CAP - 1) q0 = CAP - 1;
  if (q1 > CAP - 1) q1 = CAP - 1;
  const float4* r0 = (const float4*)(y + ((long)e0 * ME + b * CAP + q0) * C_);
  const float4* r1 = (const float4*)(y + ((long)e1 * ME + b * CAP + q1) * C_);
  const int c = threadIdx.x;  // 256 threads x float4 = 1024
  float4 a = {0.f, 0.f, 0.f, 0.f};
  if (k0) {
    float4 v = r0[c];
    a.x += p0 * v.x; a.y += p0 * v.y; a.z += p0 * v.z; a.w += p0 * v.w;
  }
  if (k1) {
    float4 v = r1[c];
    a.x += p1 * v.x; a.y += p1 * v.y; a.z += p1 * v.z; a.w += p1 * v.w;
  }
  ((float4*)(out + (long)token * C_))[c] = a;
}

// ---------------- launch ----------------
extern "C" void kernel_launch(void* const* d_in, const int* in_sizes, int n_in,
                              void* d_out, int out_size, void* d_ws, size_t ws_size,
                              hipStream_t stream) {
  const float* x = (const float*)d_in[0];
  const float* Wr = (const float*)d_in[1];
  const float* W1 = (const float*)d_in[2];
  const float* b1 = (const float*)d_in[3];
  const float* W2 = (const float*)d_in[4];
  const float* b2 = (const float*)d_in[5];
  float* out = (float*)d_out;
  char* ws = (char*)d_ws;
  // workspace layout (~400.5 MB)
  unsigned short* x_bf = (unsigned short*)(ws + 0L);          // 33,554,432
  unsigned short* W1T = (unsigned short*)(ws + 33554432L);    // 67,108,864  [E][H][C]
  unsigned short* W2T = (unsigned short*)(ws + 100663296L);   // 67,108,864  [E][C][H]
  unsigned short* h = (unsigned short*)(ws + 167772160L);     // 167,772,160 [NROWS][H]
  float* y = (float*)(ws + 335544320L);                       // 83,886,080  [NROWS][C]
  int* es = (int*)(ws + 419430400L);                          // 131,072
  float* ps = (float*)(ws + 419561472L);                      // 131,072
  int* pos = (int*)(ws + 419692544L);                         // 131,072
  int* tsrc = (int*)(ws + 419823616L);                        // 81,920

  cvt_transpose<<<dim3(16, 64, 8), 256, 0, stream>>>(W1, W1T, C_, H_);
  cvt_transpose<<<dim3(64, 16, 8), 256, 0, stream>>>(W2, W2T, H_, C_);
  router_cvt<<<4096, 256, 0, stream>>>(x, Wr, es, ps, x_bf);
  hipMemsetAsync(tsrc, 0xFF, NROWS * sizeof(int), stream);
  positions<<<8, 64, 0, stream>>>(es, pos, tsrc);
  // GEMM1: per-expert M=2560, N=4096 (NT=32): grid 8*32*20 = 5120
  moe_gemm<true, true><<<5120, 256, 0, stream>>>(x_bf, W1T, b1, tsrc, h, C_, H_, 32);
  // GEMM2: N=1024 (NT=8): grid 8*8*20 = 1280
  moe_gemm<false, false><<<1280, 256, 0, stream>>>(h, W2T, b2, nullptr, y, H_, C_, 8);
  combine<<<16384, 256, 0, stream>>>(y, es, ps, pos, out);
}

// Round 3
// 565.149 us; speedup vs baseline: 1.3087x; 1.1684x over previous
//
#include <hip/hip_runtime.h>

// Problem constants (fixed by setup_inputs)
#define B_ 8
#define T_ 2048
#define C_ 1024
#define H_ 4096
#define E_ 8
#define S_ (2 * T_)          // slots per batch row (K=2)
#define CAP 320              // int(T/E * 1.25)
#define ME 2560              // rows per expert = B_*CAP (20 x 128)
#define NROWS (E_ * ME)      // 20480 bucket rows

typedef __attribute__((ext_vector_type(8))) short short8;
typedef __attribute__((ext_vector_type(4))) float f32x4;

__device__ __forceinline__ unsigned short f2bf(float f) {
  unsigned u = __float_as_uint(f);
  unsigned r = 0x7FFFu + ((u >> 16) & 1u);   // RNE, no NaN in this data
  return (unsigned short)((u + r) >> 16);
}
__device__ __forceinline__ float bf2f(unsigned short u) {
  return __uint_as_float(((unsigned)u) << 16);
}

__device__ __forceinline__ void gload_lds16(const void* g, void* l) {
  __builtin_amdgcn_global_load_lds(
      (const __attribute__((address_space(1))) unsigned int*)g,
      (__attribute__((address_space(3))) unsigned int*)l, 16, 0, 0);
}

// ---------------- weight transpose+convert ----------------
// in: [R][Cc] fp32 (expert blockIdx.z) -> out: [Cc][R] bf16
__global__ void cvt_transpose(const float* __restrict__ in,
                              unsigned short* __restrict__ out, int R, int Cc) {
  __shared__ float t[64][65];
  const int tid = threadIdx.x;
  const long eoff = (long)blockIdx.z * R * Cc;
  const int r0 = blockIdx.x * 64, c0 = blockIdx.y * 64;
#pragma unroll
  for (int it = 0; it < 4; ++it) {
    int r = it * 16 + (tid >> 4);
    int c = (tid & 15) * 4;
    float4 v = *(const float4*)(in + eoff + (long)(r0 + r) * Cc + c0 + c);
    t[r][c] = v.x; t[r][c + 1] = v.y; t[r][c + 2] = v.z; t[r][c + 3] = v.w;
  }
  __syncthreads();
#pragma unroll
  for (int it = 0; it < 4; ++it) {
    int oc = it * 16 + (tid >> 4);   // column index (output row c0+oc)
    int orr = (tid & 15) * 4;        // original rows r0+orr..+3 (output cols)
    union { unsigned short u[4]; unsigned long long ll; } o;
    o.u[0] = f2bf(t[orr + 0][oc]); o.u[1] = f2bf(t[orr + 1][oc]);
    o.u[2] = f2bf(t[orr + 2][oc]); o.u[3] = f2bf(t[orr + 3][oc]);
    *(unsigned long long*)(out + eoff + (long)(c0 + oc) * R + r0 + orr) = o.ll;
  }
}

// ---------------- fused router + x->bf16 convert: one wave per token --------
__global__ void router_cvt(const float* __restrict__ x, const float* __restrict__ Wr,
                           int* __restrict__ es, float* __restrict__ ps,
                           unsigned short* __restrict__ x_bf) {
  const int token = blockIdx.x * 4 + (threadIdx.x >> 6);
  const int lane = threadIdx.x & 63;
  const float* xr = x + (long)token * C_;
  float acc[8] = {0, 0, 0, 0, 0, 0, 0, 0};
#pragma unroll
  for (int j = 0; j < 4; ++j) {
    int c = j * 256 + lane * 4;
    float4 xv = *(const float4*)(xr + c);
    union { unsigned short u[4]; unsigned long long ll; } o;
    o.u[0] = f2bf(xv.x); o.u[1] = f2bf(xv.y); o.u[2] = f2bf(xv.z); o.u[3] = f2bf(xv.w);
    *(unsigned long long*)(x_bf + (long)token * C_ + c) = o.ll;
    const float xe[4] = {xv.x, xv.y, xv.z, xv.w};
#pragma unroll
    for (int i = 0; i < 4; ++i) {
      const float4* wr = (const float4*)(Wr + (long)(c + i) * 8);
      float4 w0 = wr[0], w1 = wr[1];
      float v = xe[i];
      acc[0] += v * w0.x; acc[1] += v * w0.y; acc[2] += v * w0.z; acc[3] += v * w0.w;
      acc[4] += v * w1.x; acc[5] += v * w1.y; acc[6] += v * w1.z; acc[7] += v * w1.w;
    }
  }
#pragma unroll
  for (int off = 32; off >= 1; off >>= 1)
#pragma unroll
    for (int e = 0; e < 8; ++e) acc[e] += __shfl_xor(acc[e], off);
  float mx = acc[0];
#pragma unroll
  for (int e = 1; e < 8; ++e) mx = fmaxf(mx, acc[e]);
  float pr[8], se = 0.f;
#pragma unroll
  for (int e = 0; e < 8; ++e) { pr[e] = expf(acc[e] - mx); se += pr[e]; }
  float inv = 1.f / se;
  // top-2 on probs, jax tie-break: lower index wins on equality (strict >)
  int e0 = 0; float v0 = pr[0];
#pragma unroll
  for (int e = 1; e < 8; ++e) if (pr[e] > v0) { v0 = pr[e]; e0 = e; }
  int e1 = -1; float v1 = -1.f;
#pragma unroll
  for (int e = 0; e < 8; ++e) if (e != e0 && pr[e] > v1) { v1 = pr[e]; e1 = e; }
  if (lane == 0) {
    es[2 * token] = e0;     ps[2 * token] = v0 * inv;
    es[2 * token + 1] = e1; ps[2 * token + 1] = v1 * inv;
  }
}

// ---------------- positions: sequential scan per batch row ----------------
// tsrc[e*ME + b*CAP + pos] = global x row (b*T + t); -1 where bucket empty.
__global__ void positions(const int* __restrict__ es, int* __restrict__ pos,
                          int* __restrict__ tsrc) {
  const int b = blockIdx.x;
  const int lane = threadIdx.x;  // 64 threads
  int cnt[8] = {0, 0, 0, 0, 0, 0, 0, 0};
  unsigned long long below = (1ULL << lane) - 1ULL;
  int e_next = es[(long)b * S_ + lane];
  for (int chunk = 0; chunk < S_ / 64; ++chunk) {
    int e = e_next;
    if (chunk + 1 < S_ / 64) e_next = es[(long)b * S_ + (chunk + 1) * 64 + lane];
    int myPos = 0;
#pragma unroll
    for (int ei = 0; ei < 8; ++ei) {
      unsigned long long m = __ballot(e == ei);
      if (e == ei) myPos = cnt[ei] + __popcll(m & below);
      cnt[ei] += __popcll(m);
    }
    int s = chunk * 64 + lane;
    pos[(long)b * S_ + s] = myPos;
    if (myPos < CAP)
      tsrc[(long)e * ME + b * CAP + myPos] = b * T_ + (s >> 1);
  }
}

// ---------------- grouped MFMA GEMM, m97 structure (128x128 tile) ----------
// Per-expert M space = ME (2560) contiguous rows. 1D grid, XCD-chunked so each
// XCD owns one expert; mt fastest -> B-panel L2 reuse x20.
// A (bf16): GATHER ? x_bf [B*T][Kdim] gathered via tsrc : h [NROWS][Kdim]
// BT (bf16): [E][N][Kdim] (pre-transposed, K-contiguous)
// out (bf16): RELU ? relu(acc+bias) : acc+bias
// __launch_bounds__(256,3): force >=3 waves/SIMD (reg cap 170) — round-2 PMC
// showed 2 waves/SIMD (Occ 22%, MfmaUtil 26.6%) was the limiter vs m97's 3.
template <bool GATHER, bool RELU>
__global__ __launch_bounds__(256, 3) void moe_gemm(
    const unsigned short* __restrict__ A, const unsigned short* __restrict__ BT,
    const float* __restrict__ bias, const int* __restrict__ tsrc,
    unsigned short* __restrict__ outp, const int Kdim, const int N, const int NT) {
  constexpr int BM = 128, BN = 128, BK = 64;
  constexpr int MT = ME / BM;  // 20
  __shared__ unsigned short As[BM * BK];  // 16 KB, XOR-swizzled 16B slots
  __shared__ unsigned short Bs[BN * BK];  // 16 KB
  const int tid = threadIdx.x, lane = tid & 63, w = tid >> 6;

  // XCD-aware swizzle: grid = E_*NT*MT, always divisible by 8.
  const int nwg = E_ * NT * MT;
  const int chunk = nwg >> 3;
  const int swz = (blockIdx.x & 7) * chunk + (blockIdx.x >> 3);
  const int e = swz / (NT * MT);
  const int rem = swz % (NT * MT);
  const int nt = rem / MT, mt = rem % MT;
  const int n0 = nt * BN;

  // staging: wave w covers A rows [w*32,w*32+32) in 4 issues of 8 rows; same B.
  // LDS linear dest + pre-swizzled global source slot (j ^ (row&7)) so the
  // swizzled ds_read below is the matching involution (guide rule #21).
  const unsigned short* aPtr[4];
#pragma unroll
  for (int i = 0; i < 4; ++i) {
    int ra = w * 32 + i * 8 + (lane >> 3);
    int j = lane & 7;
    long rowbase;
    if constexpr (GATHER) {
      int xrow = tsrc[(long)e * ME + mt * BM + ra];
      if (xrow < 0) xrow = 0;  // empty bucket row: garbage, never gathered back
      rowbase = (long)xrow * Kdim;
    } else {
      rowbase = ((long)e * ME + mt * BM + ra) * (long)Kdim;
    }
    aPtr[i] = A + rowbase + ((j ^ (ra & 7)) << 3);
  }
  const unsigned short* bPtr[4];
#pragma unroll
  for (int i = 0; i < 4; ++i) {
    int rb = w * 32 + i * 8 + (lane >> 3);
    int j = lane & 7;
    bPtr[i] = BT + ((long)e * N + n0 + rb) * (long)Kdim + ((j ^ (rb & 7)) << 3);
  }

  const int wm = w >> 1, wn = w & 1;   // 2x2 waves, each 64x64 output
  f32x4 acc[4][4];
#pragma unroll
  for (int m = 0; m < 4; ++m)
#pragma unroll
    for (int n = 0; n < 4; ++n) acc[m][n] = (f32x4){0.f, 0.f, 0.f, 0.f};

  int arow[4], brow[4];
#pragma unroll
  for (int i = 0; i < 4; ++i) {
    arow[i] = wm * 64 + i * 16 + (lane & 15);
    brow[i] = wn * 64 + i * 16 + (lane & 15);
  }
  const int jjb = lane >> 4;

  for (int kt = 0; kt < Kdim / BK; ++kt) {
#pragma unroll
    for (int i = 0; i < 4; ++i)
      gload_lds16(aPtr[i], &As[(w * 32 + i * 8) * BK]);
#pragma unroll
    for (int i = 0; i < 4; ++i)
      gload_lds16(bPtr[i], &Bs[(w * 32 + i * 8) * BK]);
#pragma unroll
    for (int i = 0; i < 4; ++i) { aPtr[i] += BK; bPtr[i] += BK; }
    __syncthreads();
#pragma unroll
    for (int s = 0; s < 2; ++s) {
      short8 af[4], bf[4];
#pragma unroll
      for (int m = 0; m < 4; ++m) {
        int slot = (s * 4 + jjb) ^ (arow[m] & 7);
        af[m] = *(const short8*)&As[arow[m] * BK + slot * 8];
      }
#pragma unroll
      for (int n = 0; n < 4; ++n) {
        int slot = (s * 4 + jjb) ^ (brow[n] & 7);
        bf[n] = *(const short8*)&Bs[brow[n] * BK + slot * 8];
      }
#pragma unroll
      for (int m = 0; m < 4; ++m)
#pragma unroll
        for (int n = 0; n < 4; ++n)
          acc[m][n] = __builtin_amdgcn_mfma_f32_16x16x32_bf16(af[m], bf[n],
                                                              acc[m][n], 0, 0, 0);
    }
    __syncthreads();
  }

  // epilogue: C/D layout col=lane&15, row=(lane>>4)*4+j  [m89]
  const long rbase = (long)e * ME + mt * BM;
#pragma unroll
  for (int m = 0; m < 4; ++m) {
#pragma unroll
    for (int n = 0; n < 4; ++n) {
      const int trow = wm * 64 + m * 16 + ((lane >> 4) << 2);
      const int col = n0 + wn * 64 + n * 16 + (lane & 15);
      const float bv = bias[(long)e * N + col];
#pragma unroll
      for (int j = 0; j < 4; ++j) {
        float v = acc[m][n][j] + bv;
        if constexpr (RELU) v = fmaxf(v, 0.f);
        outp[(rbase + trow + j) * N + col] = f2bf(v);
      }
    }
  }
}

// ---------------- combine (y in bf16) ----------------
__global__ void combine(const unsigned short* __restrict__ y,
                        const int* __restrict__ es, const float* __restrict__ ps,
                        const int* __restrict__ pos, float* __restrict__ out) {
  const int token = blockIdx.x;  // b*T + t
  const int b = token >> 11;     // T = 2048
  const int s0 = 2 * token, s1 = s0 + 1;
  int e0 = es[s0], e1 = es[s1];
  int q0 = pos[s0], q1 = pos[s1];
  float p0 = ps[s0], p1 = ps[s1];
  const bool k0 = q0 < CAP, k1 = q1 < CAP;
  if (q0 > CAP - 1) q0 = CAP - 1;
  if (q1 > CAP - 1) q1 = CAP - 1;
  const unsigned short* r0 = y + ((long)e0 * ME + b * CAP + q0) * C_;
  const unsigned short* r1 = y + ((long)e1 * ME + b * CAP + q1) * C_;
  const int c = threadIdx.x * 4;  // 256 threads x 4 cols
  float4 a = {0.f, 0.f, 0.f, 0.f};
  if (k0) {
    union { unsigned short u[4]; unsigned long long ll; } v;
    v.ll = *(const unsigned long long*)(r0 + c);
    a.x += p0 * bf2f(v.u[0]); a.y += p0 * bf2f(v.u[1]);
    a.z += p0 * bf2f(v.u[2]); a.w += p0 * bf2f(v.u[3]);
  }
  if (k1) {
    union { unsigned short u[4]; unsigned long long ll; } v;
    v.ll = *(const unsigned long long*)(r1 + c);
    a.x += p1 * bf2f(v.u[0]); a.y += p1 * bf2f(v.u[1]);
    a.z += p1 * bf2f(v.u[2]); a.w += p1 * bf2f(v.u[3]);
  }
  *(float4*)(out + (long)token * C_ + c) = a;
}

// ---------------- launch ----------------
extern "C" void kernel_launch(void* const* d_in, const int* in_sizes, int n_in,
                              void* d_out, int out_size, void* d_ws, size_t ws_size,
                              hipStream_t stream) {
  const float* x = (const float*)d_in[0];
  const float* Wr = (const float*)d_in[1];
  const float* W1 = (const float*)d_in[2];
  const float* b1 = (const float*)d_in[3];
  const float* W2 = (const float*)d_in[4];
  const float* b2 = (const float*)d_in[5];
  float* out = (float*)d_out;
  char* ws = (char*)d_ws;
  // workspace layout (~360 MB)
  unsigned short* x_bf = (unsigned short*)(ws + 0L);          // 33,554,432
  unsigned short* W1T = (unsigned short*)(ws + 33554432L);    // 67,108,864  [E][H][C]
  unsigned short* W2T = (unsigned short*)(ws + 100663296L);   // 67,108,864  [E][C][H]
  unsigned short* h = (unsigned short*)(ws + 167772160L);     // 167,772,160 [NROWS][H]
  unsigned short* y = (unsigned short*)(ws + 335544320L);     // 41,943,040  [NROWS][C] bf16
  int* es = (int*)(ws + 377487360L);                          // 131,072
  float* ps = (float*)(ws + 377618432L);                      // 131,072
  int* pos = (int*)(ws + 377749504L);                         // 131,072
  int* tsrc = (int*)(ws + 377880576L);                        // 81,920

  cvt_transpose<<<dim3(16, 64, 8), 256, 0, stream>>>(W1, W1T, C_, H_);
  cvt_transpose<<<dim3(64, 16, 8), 256, 0, stream>>>(W2, W2T, H_, C_);
  router_cvt<<<4096, 256, 0, stream>>>(x, Wr, es, ps, x_bf);
  hipMemsetAsync(tsrc, 0xFF, NROWS * sizeof(int), stream);
  positions<<<8, 64, 0, stream>>>(es, pos, tsrc);
  // GEMM1: per-expert M=2560, N=4096 (NT=32): grid 8*32*20 = 5120
  moe_gemm<true, true><<<5120, 256, 0, stream>>>(x_bf, W1T, b1, tsrc, h, C_, H_, 32);
  // GEMM2: N=1024 (NT=8): grid 8*8*20 = 1280
  moe_gemm<false, false><<<1280, 256, 0, stream>>>(h, W2T, b2, nullptr, y, H_, C_, 8);
  combine<<<16384, 256, 0, stream>>>(y, es, ps, pos, out);
}